// Round 1
// 123.000 us; speedup vs baseline: 1.0048x; 1.0048x over previous
//
#include <hip/hip_runtime.h>
#include <hip/hip_bf16.h>

// MHGAT: B=8, J=2048, C=256, K=32, H=8, D=32; M = B*J = 16384
// World: all float tensors fp32; nbr int32; out fp32.
// Round 13: r12 base (best: 123.6) + Q/K stored as f16 and attn Phase A
// rewritten with v_dot2_f32_f16 (fdot2): 1 instr per packed pair instead of
// upk(2 ops)+2 fma, and the q-row unpack disappears. VP stays bf16 (Phase B's
// upk shift-trick needs bf16). f16 has MORE mantissa than bf16 -> accuracy
// can only improve. fdot2 guarded by __has_builtin with scalar-f16 fallback.

typedef short bf16x8 __attribute__((ext_vector_type(8)));
typedef float f32x4  __attribute__((ext_vector_type(4)));
typedef float f32x2  __attribute__((ext_vector_type(2)));
typedef _Float16 h16x2 __attribute__((ext_vector_type(2)));

__device__ __forceinline__ float bf2f(unsigned short u) {
    union { unsigned int i; float f; } c; c.i = ((unsigned int)u) << 16; return c.f;
}
__device__ __forceinline__ unsigned short f2bf(float f) {
    union { float f; unsigned int i; } c; c.f = f;
    unsigned int r = c.i + 0x7FFFu + ((c.i >> 16) & 1u);  // RNE
    return (unsigned short)(r >> 16);
}
__device__ __forceinline__ unsigned short f2h(float f) {
    union { _Float16 h; unsigned short u; } c; c.h = (_Float16)f;  // v_cvt_f16_f32 RNE
    return c.u;
}
// 2 bf16 packed in a dword -> 2 fp32 with exactly 2 bit-ops.
__device__ __forceinline__ f32x2 upk(unsigned int u) {
    union { unsigned int i; float f; } lo, hi;
    lo.i = u << 16;
    hi.i = u & 0xffff0000u;
    return (f32x2){lo.f, hi.f};
}

// packed-f16 dot2 with f32 accumulate: one v_dot2_f32_f16 when available.
#if defined(__has_builtin)
#if __has_builtin(__builtin_amdgcn_fdot2)
#define HAVE_FDOT2 1
#endif
#endif
__device__ __forceinline__ float dot2acc(unsigned int a, unsigned int b, float acc) {
#ifdef HAVE_FDOT2
    union { unsigned int u; h16x2 v; } ca, cb;
    ca.u = a; cb.u = b;
    return __builtin_amdgcn_fdot2(ca.v, cb.v, acc, false);
#else
    union { unsigned int u; _Float16 h[2]; } ca, cb;
    ca.u = a; cb.u = b;
    return acc + (float)ca.h[0] * (float)cb.h[0] + (float)ca.h[1] * (float)cb.h[1];
#endif
}

__device__ __forceinline__ void gld_lds16(void* lds, const void* g) {
    __builtin_amdgcn_global_load_lds(
        (const __attribute__((address_space(1))) unsigned int*)g,
        (__attribute__((address_space(3))) unsigned int*)lds,
        16, 0, 0);
}

// ---------------------------------------------------------------------------
// Prep (unchanged): x fp32->bf16; Wq/Wk transposed bf16; Weff = Wv@Wp folded.
// ---------------------------------------------------------------------------
__global__ __launch_bounds__(256) void prep(
    const float* __restrict__ x,
    const float* __restrict__ Wq, const float* __restrict__ Wk,
    const float* __restrict__ Wv, const float* __restrict__ Wp,
    unsigned short* __restrict__ xb, unsigned short* __restrict__ Wt)
{
    const int blk = blockIdx.x, tid = threadIdx.x;
    if (blk < 4096) {
        int t = blk * 256 + tid;
        float4 f = ((const float4*)x)[t];
        ushort4 u;
        u.x = f2bf(f.x); u.y = f2bf(f.y); u.z = f2bf(f.z); u.w = f2bf(f.w);
        ((ushort4*)xb)[t] = u;
        return;
    }
    int wi = blk - 4096;
    int w = wi >> 8, n = wi & 255, t = tid;       // t = k index
    if (w == 0) {
        Wt[(size_t)n * 256 + t] = f2bf(Wq[(size_t)t * 256 + n]);
    } else if (w == 1) {
        Wt[(size_t)(256 + n) * 256 + t] = f2bf(Wk[(size_t)t * 256 + n]);
    } else {
        int h = n >> 5, c = n & 31;
        float acc = 0.f;
#pragma unroll
        for (int d = 0; d < 32; d++)
            acc += Wv[(size_t)t * 256 + h * 32 + d] * Wp[(size_t)(h * 32 + d) * 32 + c];
        Wt[(size_t)(512 + n) * 256 + t] = f2bf(acc);
    }
}

// ---------------------------------------------------------------------------
// QKV GEMM: xb bf16 @ Wt[z][n][k] -> z 0/1 (Q,K) stored f16, z 2 (VP) bf16.
// ---------------------------------------------------------------------------
__global__ __launch_bounds__(256) void qkv_mfma(
    const unsigned short* __restrict__ xb,
    const unsigned short* __restrict__ Wt,
    unsigned short* __restrict__ Q, unsigned short* __restrict__ Kp,
    unsigned short* __restrict__ VP)
{
    __shared__ unsigned short Als[128][64];
    __shared__ unsigned short Bls[128][64];

    const unsigned short* Wb = Wt + (size_t)blockIdx.z * 65536;
    unsigned short* Y = (blockIdx.z == 0) ? Q : (blockIdx.z == 1) ? Kp : VP;
    const bool as_f16 = (blockIdx.z != 2);   // block-uniform

    const int row0 = blockIdx.x * 128;
    const int col0 = blockIdx.y * 128;
    const int tid  = threadIdx.x;
    const int w    = tid >> 6, l = tid & 63;
    const int wm   = (w >> 1) * 64, wn = (w & 1) * 64;
    const int lm   = l & 15, quad = l >> 4;

    f32x4 acc[4][4];
#pragma unroll
    for (int i = 0; i < 4; i++)
#pragma unroll
        for (int j = 0; j < 4; j++) acc[i][j] = (f32x4){0.f, 0.f, 0.f, 0.f};

    const char* Ab = (const char*)(xb + (size_t)row0 * 256);
    const char* Bb = (const char*)(Wb + (size_t)col0 * 256);

    for (int k0 = 0; k0 < 256; k0 += 64) {
#pragma unroll
        for (int i = 0; i < 4; i++) {
            int s = i * 256 + tid;
            int r = s >> 3, c = s & 7;
            size_t go = (size_t)r * 512 + (size_t)k0 * 2 + c * 16;
            gld_lds16((char*)Als + s * 16, Ab + go);
            gld_lds16((char*)Bls + s * 16, Bb + go);
        }
        __syncthreads();

#pragma unroll
        for (int kk = 0; kk < 64; kk += 32) {
            bf16x8 a[4], b[4];
#pragma unroll
            for (int tm = 0; tm < 4; tm++)
                a[tm] = *(const bf16x8*)&Als[wm + tm * 16 + lm][kk + quad * 8];
#pragma unroll
            for (int tn = 0; tn < 4; tn++)
                b[tn] = *(const bf16x8*)&Bls[wn + tn * 16 + lm][kk + quad * 8];
#pragma unroll
            for (int tm = 0; tm < 4; tm++)
#pragma unroll
                for (int tn = 0; tn < 4; tn++)
                    acc[tm][tn] = __builtin_amdgcn_mfma_f32_16x16x32_bf16(
                        a[tm], b[tn], acc[tm][tn], 0, 0, 0);
        }
        __syncthreads();
    }

#pragma unroll
    for (int tm = 0; tm < 4; tm++) {
        int rbase = row0 + wm + tm * 16 + quad * 4;
#pragma unroll
        for (int tn = 0; tn < 4; tn++) {
            int col = col0 + wn + tn * 16 + lm;
            if (as_f16) {
#pragma unroll
                for (int r = 0; r < 4; r++)
                    Y[(size_t)(rbase + r) * 256 + col] = f2h(acc[tm][tn][r]);
            } else {
#pragma unroll
                for (int r = 0; r < 4; r++)
                    Y[(size_t)(rbase + r) * 256 + col] = f2bf(acc[tm][tn][r]);
            }
        }
    }
}

// ---------------------------------------------------------------------------
// Attention v9 (r12 structure): one block per (b,j), 16384 blocks.
// XCD swizzle b = blk&7. Per-lane koff loads (half-wave-uniform address ->
// broadcast). All 8 row loads issued up front; vp values ride registers
// across the softmax barriers. 4 barriers total.
// NEW: q/k are f16; Phase A dot via v_dot2_f32_f16 (no unpack, no fma chain).
// ---------------------------------------------------------------------------
__global__ __launch_bounds__(256) void attn_all(
    const unsigned short* __restrict__ qb,   // [16384,256] f16
    const unsigned short* __restrict__ kb,   // [16384,256] f16
    const unsigned short* __restrict__ vp,   // [16384,256] bf16 (VP = v@Wp)
    const int*            __restrict__ nbr,  // [16384,32]
    float*                __restrict__ out)  // [16384,32] fp32
{
    __shared__ float sc[8 * 33];    // [h][kk]
    __shared__ float pw[8 * 33];    // [h][kk]
    __shared__ float redB[8 * 264]; // [g][e], e-stride 264
    __shared__ float red2[256];     // [e] after g-sum

    const int b   = blockIdx.x & 7;
    const int j   = blockIdx.x >> 3;
    const int bj  = (b << 11) + j;
    const int tid = threadIdx.x;

    const int w    = tid >> 6;       // wave 0..3
    const int l    = tid & 63;
    const int lh   = l & 31;         // lane within half-wave
    const int half = l >> 5;
    const int hA   = lh >> 2;        // head owning elems lh*8..lh*8+7
    const int g    = 2 * w + half;   // phase-B group 0..7
    const size_t bbase = (size_t)b << 19;   // b*2048*256
    const int* nrow = nbr + (size_t)bj * 32;

    // q fragment load (independent of everything). Stays packed f16.
    uint4 qu = *(const uint4*)(qb + (size_t)bj * 256 + lh * 8);

    // per-lane neighbor indices (half-wave-uniform addresses -> broadcast)
    int koA[4], koB[4];
#pragma unroll
    for (int p = 0; p < 4; p++) koA[p] = nrow[w * 8 + 2 * p + half] << 8;
#pragma unroll
    for (int p = 0; p < 4; p++) koB[p] = nrow[p * 8 + g] << 8;

    // ---- issue ALL 8 row loads up front ----
    uint4 ku[4], vu[4];
#pragma unroll
    for (int p = 0; p < 4; p++)
        ku[p] = *(const uint4*)(kb + bbase + koA[p] + lh * 8);
#pragma unroll
    for (int p = 0; p < 4; p++)
        vu[p] = *(const uint4*)(vp + bbase + koB[p] + lh * 8);

    // ---- Phase A: scores from ku via packed-f16 dot2 ----
#pragma unroll
    for (int p = 0; p < 4; p++) {
        const int kkA = w * 8 + 2 * p + half;
        float acc = 0.f;
        acc = dot2acc(ku[p].x, qu.x, acc);
        acc = dot2acc(ku[p].y, qu.y, acc);
        acc = dot2acc(ku[p].z, qu.z, acc);
        acc = dot2acc(ku[p].w, qu.w, acc);
        acc += __shfl_xor(acc, 1);
        acc += __shfl_xor(acc, 2);
        if ((l & 3) == 0) {
            float s = acc * 0.17677669529663687f;   // 1/sqrt(32)
            s = (s > 0.f) ? s : 0.2f * s;           // leaky_relu 0.2
            sc[hA * 33 + kkA] = s;
        }
    }
    __syncthreads();   // B1: sc ready

    // ---- softmax over kk per head: lane=(kk2,h2) ----
    {
        const int h2  = 2 * w + half;
        const int kk2 = lh;
        float s = sc[h2 * 33 + kk2];
        float mx = s;
#pragma unroll
        for (int m = 16; m >= 1; m >>= 1) mx = fmaxf(mx, __shfl_xor(mx, m));
        float e = __expf(s - mx);
        float sum = e;
#pragma unroll
        for (int m = 16; m >= 1; m >>= 1) sum += __shfl_xor(sum, m);
        pw[h2 * 33 + kk2] = e / sum;
    }
    __syncthreads();   // B2: pw ready

    // ---- Phase B: weighted accumulate from prefetched vu (bf16 upk) ----
    {
        f32x2 a0 = (f32x2){0.f,0.f}, a1 = a0, a2v = a0, a3 = a0;
#pragma unroll
        for (int p = 0; p < 4; p++) {
            const int kkB = p * 8 + g;
            const float wgt = pw[hA * 33 + kkB];
            const f32x2 w2 = (f32x2){wgt, wgt};
            a0  += upk(vu[p].x) * w2;
            a1  += upk(vu[p].y) * w2;
            a2v += upk(vu[p].z) * w2;
            a3  += upk(vu[p].w) * w2;
        }
        float* rb = &redB[g * 264 + lh * 8];
        *(float4*)(rb)     = make_float4(a0.x, a0.y, a1.x, a1.y);
        *(float4*)(rb + 4) = make_float4(a2v.x, a2v.y, a3.x, a3.y);
    }
    __syncthreads();   // B3: redB ready

    // ---- tail: g-sum with all 256 threads, then h-sum with 32 ----
    {
        float s = 0.f;
#pragma unroll
        for (int gg = 0; gg < 8; gg++) s += redB[gg * 264 + tid];
        red2[tid] = s;
    }
    __syncthreads();   // B4: red2 ready

    if (tid < 32) {
        float o = 0.f;
#pragma unroll
        for (int h = 0; h < 8; h++) o += red2[h * 32 + tid];
        out[(size_t)bj * 32 + tid] = o;
    }
}

// ---------------------------------------------------------------------------
// Tier 0 fallback (tiny ws): fully fused fp32, zero workspace. Slow, correct.
// ---------------------------------------------------------------------------
__global__ __launch_bounds__(256) void fused_all(
    const float* __restrict__ X, const int* __restrict__ nbr,
    const float* __restrict__ Wq, const float* __restrict__ Wk,
    const float* __restrict__ Wv, const float* __restrict__ Wp,
    float* __restrict__ out)
{
    __shared__ float xr[256], qrow[256], xn[256];
    __shared__ float vn[32][256];
    __shared__ int   nb[32];
    __shared__ float sc[32][8], pwv[32][8];
    __shared__ float sp[256], hd[256];
    __shared__ float red[8][32];

    const int bj = blockIdx.x, b = bj >> 11, tid = threadIdx.x;

    xr[tid] = X[(size_t)bj * 256 + tid];
    if (tid < 32) nb[tid] = nbr[(size_t)bj * 32 + tid];
    __syncthreads();

    {
        float acc = 0.f;
#pragma unroll 8
        for (int c = 0; c < 256; c++) acc += xr[c] * Wq[(size_t)c * 256 + tid];
        qrow[tid] = acc;
    }
    __syncthreads();

    for (int i = 0; i < 32; i++) {
        size_t r = (size_t)(b * 2048 + nb[i]);
        xn[tid] = X[r * 256 + tid];
        __syncthreads();
        float ka = 0.f, va = 0.f;
#pragma unroll 8
        for (int c = 0; c < 256; c++) {
            float xc = xn[c];
            ka += xc * Wk[(size_t)c * 256 + tid];
            va += xc * Wv[(size_t)c * 256 + tid];
        }
        vn[i][tid] = va;
        sp[tid] = qrow[tid] * ka;
        __syncthreads();
        if (tid < 8) {
            float s = 0.f;
#pragma unroll
            for (int d = 0; d < 32; d++) s += sp[tid * 32 + d];
            s *= 0.17677669529663687f;
            s = (s > 0.f) ? s : 0.2f * s;
            sc[i][tid] = s;
        }
        __syncthreads();
    }

    {
        const int h = tid & 7, kk = tid >> 3;
        float mx = -1e30f;
#pragma unroll
        for (int i = 0; i < 32; i++) mx = fmaxf(mx, sc[i][h]);
        float ssum = 0.f;
#pragma unroll
        for (int i = 0; i < 32; i++) ssum += __expf(sc[i][h] - mx);
        pwv[kk][h] = __expf(sc[kk][h] - mx) / ssum;
    }
    __syncthreads();

    {
        const int h2 = tid >> 5;
        float acc = 0.f;
#pragma unroll 8
        for (int i = 0; i < 32; i++) acc += pwv[i][h2] * vn[i][tid];
        hd[tid] = acc;
    }
    __syncthreads();

    {
        const int c = tid & 31, ch = tid >> 5;
        float p = 0.f;
#pragma unroll
        for (int i = 0; i < 32; i++) { int r = ch * 32 + i; p += hd[r] * Wp[r * 32 + c]; }
        red[ch][c] = p;
    }
    __syncthreads();

    if (tid < 32) {
        float o = 0.f;
#pragma unroll
        for (int i = 0; i < 8; i++) o += red[i][tid];
        out[(size_t)bj * 32 + tid] = o;
    }
}

extern "C" void kernel_launch(void* const* d_in, const int* in_sizes, int n_in,
                              void* d_out, int out_size, void* d_ws, size_t ws_size,
                              hipStream_t stream) {
    const float* x   = (const float*)d_in[0];
    const int*   nbr = (const int*)d_in[1];
    const float* Wq  = (const float*)d_in[2];
    const float* Wk  = (const float*)d_in[3];
    const float* Wv  = (const float*)d_in[4];
    const float* Wp  = (const float*)d_in[5];
    float*       out = (float*)d_out;

    const size_t ME   = (size_t)16384 * 256;
    const size_t need = (4 * ME + 3 * 65536) * sizeof(unsigned short);  // ~34 MB

    if (ws_size >= need) {
        unsigned short* q  = (unsigned short*)d_ws;
        unsigned short* k  = q + ME;
        unsigned short* vp = k + ME;
        unsigned short* xb = vp + ME;
        unsigned short* Wt = xb + ME;

        prep<<<4096 + 768, 256, 0, stream>>>(x, Wq, Wk, Wv, Wp, xb, Wt);
        qkv_mfma<<<dim3(128, 2, 3), 256, 0, stream>>>(xb, Wt, q, k, vp);
        attn_all<<<16384, 256, 0, stream>>>(q, k, vp, nbr, out);
    } else {
        fused_all<<<16384, 256, 0, stream>>>(x, nbr, Wq, Wk, Wv, Wp, out);
    }
}

// Round 2
// 119.258 us; speedup vs baseline: 1.0363x; 1.0314x over previous
//
#include <hip/hip_runtime.h>
#include <hip/hip_bf16.h>

// MHGAT: B=8, J=2048, C=256, K=32, H=8, D=32; M = B*J = 16384
// World: all float tensors fp32; nbr int32; out fp32.
// Round 14: r13 base (123.0) + attention rewritten as ONE WAVE per (b,j):
// zero barriers, zero LDS. Lane l covers elems lh*8..+8 (head hA=lh>>2);
// after the xor-1/xor-2 score reduce the softmax is duplicated across each
// head's 4 sub-lanes, so every lane already owns the Phase-B weights it
// needs -- no broadcast, no LDS round-trips. 16 k-row + 16 vp-row loads
// issued as flat batches; vp loads issued before softmax ALU to hide L2
// latency. prep/qkv_mfma unchanged from r13 (Q/K f16 + fdot2 kept).

typedef short bf16x8 __attribute__((ext_vector_type(8)));
typedef float f32x4  __attribute__((ext_vector_type(4)));
typedef float f32x2  __attribute__((ext_vector_type(2)));
typedef _Float16 h16x2 __attribute__((ext_vector_type(2)));

__device__ __forceinline__ float bf2f(unsigned short u) {
    union { unsigned int i; float f; } c; c.i = ((unsigned int)u) << 16; return c.f;
}
__device__ __forceinline__ unsigned short f2bf(float f) {
    union { float f; unsigned int i; } c; c.f = f;
    unsigned int r = c.i + 0x7FFFu + ((c.i >> 16) & 1u);  // RNE
    return (unsigned short)(r >> 16);
}
__device__ __forceinline__ unsigned short f2h(float f) {
    union { _Float16 h; unsigned short u; } c; c.h = (_Float16)f;  // v_cvt_f16_f32 RNE
    return c.u;
}
// 2 bf16 packed in a dword -> 2 fp32 with exactly 2 bit-ops.
__device__ __forceinline__ f32x2 upk(unsigned int u) {
    union { unsigned int i; float f; } lo, hi;
    lo.i = u << 16;
    hi.i = u & 0xffff0000u;
    return (f32x2){lo.f, hi.f};
}

// packed-f16 dot2 with f32 accumulate: one v_dot2_f32_f16 when available.
#if defined(__has_builtin)
#if __has_builtin(__builtin_amdgcn_fdot2)
#define HAVE_FDOT2 1
#endif
#endif
__device__ __forceinline__ float dot2acc(unsigned int a, unsigned int b, float acc) {
#ifdef HAVE_FDOT2
    union { unsigned int u; h16x2 v; } ca, cb;
    ca.u = a; cb.u = b;
    return __builtin_amdgcn_fdot2(ca.v, cb.v, acc, false);
#else
    union { unsigned int u; _Float16 h[2]; } ca, cb;
    ca.u = a; cb.u = b;
    return acc + (float)ca.h[0] * (float)cb.h[0] + (float)ca.h[1] * (float)cb.h[1];
#endif
}

__device__ __forceinline__ void gld_lds16(void* lds, const void* g) {
    __builtin_amdgcn_global_load_lds(
        (const __attribute__((address_space(1))) unsigned int*)g,
        (__attribute__((address_space(3))) unsigned int*)lds,
        16, 0, 0);
}

// ---------------------------------------------------------------------------
// Prep (unchanged): x fp32->bf16; Wq/Wk transposed bf16; Weff = Wv@Wp folded.
// ---------------------------------------------------------------------------
__global__ __launch_bounds__(256) void prep(
    const float* __restrict__ x,
    const float* __restrict__ Wq, const float* __restrict__ Wk,
    const float* __restrict__ Wv, const float* __restrict__ Wp,
    unsigned short* __restrict__ xb, unsigned short* __restrict__ Wt)
{
    const int blk = blockIdx.x, tid = threadIdx.x;
    if (blk < 4096) {
        int t = blk * 256 + tid;
        float4 f = ((const float4*)x)[t];
        ushort4 u;
        u.x = f2bf(f.x); u.y = f2bf(f.y); u.z = f2bf(f.z); u.w = f2bf(f.w);
        ((ushort4*)xb)[t] = u;
        return;
    }
    int wi = blk - 4096;
    int w = wi >> 8, n = wi & 255, t = tid;       // t = k index
    if (w == 0) {
        Wt[(size_t)n * 256 + t] = f2bf(Wq[(size_t)t * 256 + n]);
    } else if (w == 1) {
        Wt[(size_t)(256 + n) * 256 + t] = f2bf(Wk[(size_t)t * 256 + n]);
    } else {
        int h = n >> 5, c = n & 31;
        float acc = 0.f;
#pragma unroll
        for (int d = 0; d < 32; d++)
            acc += Wv[(size_t)t * 256 + h * 32 + d] * Wp[(size_t)(h * 32 + d) * 32 + c];
        Wt[(size_t)(512 + n) * 256 + t] = f2bf(acc);
    }
}

// ---------------------------------------------------------------------------
// QKV GEMM: xb bf16 @ Wt[z][n][k] -> z 0/1 (Q,K) stored f16, z 2 (VP) bf16.
// ---------------------------------------------------------------------------
__global__ __launch_bounds__(256) void qkv_mfma(
    const unsigned short* __restrict__ xb,
    const unsigned short* __restrict__ Wt,
    unsigned short* __restrict__ Q, unsigned short* __restrict__ Kp,
    unsigned short* __restrict__ VP)
{
    __shared__ unsigned short Als[128][64];
    __shared__ unsigned short Bls[128][64];

    const unsigned short* Wb = Wt + (size_t)blockIdx.z * 65536;
    unsigned short* Y = (blockIdx.z == 0) ? Q : (blockIdx.z == 1) ? Kp : VP;
    const bool as_f16 = (blockIdx.z != 2);   // block-uniform

    const int row0 = blockIdx.x * 128;
    const int col0 = blockIdx.y * 128;
    const int tid  = threadIdx.x;
    const int w    = tid >> 6, l = tid & 63;
    const int wm   = (w >> 1) * 64, wn = (w & 1) * 64;
    const int lm   = l & 15, quad = l >> 4;

    f32x4 acc[4][4];
#pragma unroll
    for (int i = 0; i < 4; i++)
#pragma unroll
        for (int j = 0; j < 4; j++) acc[i][j] = (f32x4){0.f, 0.f, 0.f, 0.f};

    const char* Ab = (const char*)(xb + (size_t)row0 * 256);
    const char* Bb = (const char*)(Wb + (size_t)col0 * 256);

    for (int k0 = 0; k0 < 256; k0 += 64) {
#pragma unroll
        for (int i = 0; i < 4; i++) {
            int s = i * 256 + tid;
            int r = s >> 3, c = s & 7;
            size_t go = (size_t)r * 512 + (size_t)k0 * 2 + c * 16;
            gld_lds16((char*)Als + s * 16, Ab + go);
            gld_lds16((char*)Bls + s * 16, Bb + go);
        }
        __syncthreads();

#pragma unroll
        for (int kk = 0; kk < 64; kk += 32) {
            bf16x8 a[4], b[4];
#pragma unroll
            for (int tm = 0; tm < 4; tm++)
                a[tm] = *(const bf16x8*)&Als[wm + tm * 16 + lm][kk + quad * 8];
#pragma unroll
            for (int tn = 0; tn < 4; tn++)
                b[tn] = *(const bf16x8*)&Bls[wn + tn * 16 + lm][kk + quad * 8];
#pragma unroll
            for (int tm = 0; tm < 4; tm++)
#pragma unroll
                for (int tn = 0; tn < 4; tn++)
                    acc[tm][tn] = __builtin_amdgcn_mfma_f32_16x16x32_bf16(
                        a[tm], b[tn], acc[tm][tn], 0, 0, 0);
        }
        __syncthreads();
    }

#pragma unroll
    for (int tm = 0; tm < 4; tm++) {
        int rbase = row0 + wm + tm * 16 + quad * 4;
#pragma unroll
        for (int tn = 0; tn < 4; tn++) {
            int col = col0 + wn + tn * 16 + lm;
            if (as_f16) {
#pragma unroll
                for (int r = 0; r < 4; r++)
                    Y[(size_t)(rbase + r) * 256 + col] = f2h(acc[tm][tn][r]);
            } else {
#pragma unroll
                for (int r = 0; r < 4; r++)
                    Y[(size_t)(rbase + r) * 256 + col] = f2bf(acc[tm][tn][r]);
            }
        }
    }
}

// ---------------------------------------------------------------------------
// Attention v10: ONE WAVE per (b,j). 4096 blocks x 256 threads (4 waves).
// Zero barriers, zero LDS. XCD swizzle: b = blk&7 keeps a batch's k/vp/q
// slices (3 MB) resident in one XCD's 4 MB L2.
//
// Lane map: lh = l&31 covers elements lh*8..lh*8+7 (head hA = lh>>2, dim
// quad sub = lh&3). Half h5 = l>>5 owns neighbor rows of parity h5:
// iteration r handles row 2r+h5. Score reduce xor-1/xor-2 duplicates each
// head's score across its 4 sub-lanes -> softmax (in-lane over 16 rows +
// one xor-32 shfl) lands the exact Phase-B weight in every lane. Output:
// xor-32 half merge + xor-4/8/16 head-sum tree; lanes 0..3 store.
// ---------------------------------------------------------------------------
__global__ __launch_bounds__(256) void attn_wave(
    const unsigned short* __restrict__ qb,   // [16384,256] f16
    const unsigned short* __restrict__ kb,   // [16384,256] f16
    const unsigned short* __restrict__ vp,   // [16384,256] bf16 (VP = v@Wp)
    const int*            __restrict__ nbr,  // [16384,32]
    float*                __restrict__ out)  // [16384,32] fp32
{
    const int beta = blockIdx.x;
    const int b    = beta & 7;
    const int jt   = beta >> 3;
    const int tid  = threadIdx.x;
    const int w    = tid >> 6;
    const int l    = tid & 63;
    const int lh   = l & 31;
    const int h5   = l >> 5;
    const int bj   = (b << 11) + jt * 4 + w;
    const size_t bbase = (size_t)b << 19;        // b*2048*256 elements
    const int* nrow = nbr + (size_t)bj * 32;

    // all 32 neighbor offsets: lane lh holds nbr[lh]; distribute via shfl.
    int ko = nrow[lh] << 8;                      // element offset of row
    int koff[16];
#pragma unroll
    for (int r = 0; r < 16; r++) koff[r] = __shfl(ko, 2 * r + h5);

    // q fragment (packed f16, 8 elems at lh*8)
    uint4 qu = *(const uint4*)(qb + (size_t)bj * 256 + lh * 8);

    // ---- Phase A: 16 k-row loads (batched, vmcnt-counted) ----
    uint4 kr[16];
#pragma unroll
    for (int r = 0; r < 16; r++)
        kr[r] = *(const uint4*)(kb + bbase + koff[r] + lh * 8);

    float s[16];
#pragma unroll
    for (int r = 0; r < 16; r++) {
        float a = 0.f;
        a = dot2acc(kr[r].x, qu.x, a);
        a = dot2acc(kr[r].y, qu.y, a);
        a = dot2acc(kr[r].z, qu.z, a);
        a = dot2acc(kr[r].w, qu.w, a);
        a += __shfl_xor(a, 1);
        a += __shfl_xor(a, 2);                   // score dup'd across 4 sub-lanes
        a *= 0.17677669529663687f;               // 1/sqrt(32)
        s[r] = (a > 0.f) ? a : 0.2f * a;         // leaky_relu 0.2
    }

    // ---- issue vp loads BEFORE softmax ALU (latency hides under it) ----
    uint4 vr[16];
#pragma unroll
    for (int r = 0; r < 16; r++)
        vr[r] = *(const uint4*)(vp + bbase + koff[r] + lh * 8);

    // ---- softmax per head over 32 rows (16 in-lane + cross-half xor-32) --
    float m = s[0];
#pragma unroll
    for (int r = 1; r < 16; r++) m = fmaxf(m, s[r]);
    m = fmaxf(m, __shfl_xor(m, 32));
    float sum = 0.f;
#pragma unroll
    for (int r = 0; r < 16; r++) { s[r] = __expf(s[r] - m); sum += s[r]; }
    sum += __shfl_xor(sum, 32);
    const float inv = 1.0f / sum;
#pragma unroll
    for (int r = 0; r < 16; r++) s[r] *= inv;    // every lane owns its weights

    // ---- Phase B: weighted accumulate over this lane's 16 rows ----
    f32x2 a0 = (f32x2){0.f, 0.f}, a1 = a0, a2 = a0, a3 = a0;
#pragma unroll
    for (int r = 0; r < 16; r++) {
        const f32x2 w2 = (f32x2){s[r], s[r]};
        a0 += upk(vr[r].x) * w2;
        a1 += upk(vr[r].y) * w2;
        a2 += upk(vr[r].z) * w2;
        a3 += upk(vr[r].w) * w2;
    }

    // ---- merge: halves (xor 32), then heads (xor 4,8,16) ----
    float o[8] = {a0.x, a0.y, a1.x, a1.y, a2.x, a2.y, a3.x, a3.y};
#pragma unroll
    for (int i = 0; i < 8; i++) o[i] += __shfl_xor(o[i], 32);
#pragma unroll
    for (int i = 0; i < 8; i++) o[i] += __shfl_xor(o[i], 4);
#pragma unroll
    for (int i = 0; i < 8; i++) o[i] += __shfl_xor(o[i], 8);
#pragma unroll
    for (int i = 0; i < 8; i++) o[i] += __shfl_xor(o[i], 16);

    if (l < 4) {                                 // sub = l, dims l*8..l*8+7
        float* op = out + (size_t)bj * 32 + l * 8;
        *(float4*)(op)     = make_float4(o[0], o[1], o[2], o[3]);
        *(float4*)(op + 4) = make_float4(o[4], o[5], o[6], o[7]);
    }
}

// ---------------------------------------------------------------------------
// Tier 0 fallback (tiny ws): fully fused fp32, zero workspace. Slow, correct.
// ---------------------------------------------------------------------------
__global__ __launch_bounds__(256) void fused_all(
    const float* __restrict__ X, const int* __restrict__ nbr,
    const float* __restrict__ Wq, const float* __restrict__ Wk,
    const float* __restrict__ Wv, const float* __restrict__ Wp,
    float* __restrict__ out)
{
    __shared__ float xr[256], qrow[256], xn[256];
    __shared__ float vn[32][256];
    __shared__ int   nb[32];
    __shared__ float sc[32][8], pwv[32][8];
    __shared__ float sp[256], hd[256];
    __shared__ float red[8][32];

    const int bj = blockIdx.x, b = bj >> 11, tid = threadIdx.x;

    xr[tid] = X[(size_t)bj * 256 + tid];
    if (tid < 32) nb[tid] = nbr[(size_t)bj * 32 + tid];
    __syncthreads();

    {
        float acc = 0.f;
#pragma unroll 8
        for (int c = 0; c < 256; c++) acc += xr[c] * Wq[(size_t)c * 256 + tid];
        qrow[tid] = acc;
    }
    __syncthreads();

    for (int i = 0; i < 32; i++) {
        size_t r = (size_t)(b * 2048 + nb[i]);
        xn[tid] = X[r * 256 + tid];
        __syncthreads();
        float ka = 0.f, va = 0.f;
#pragma unroll 8
        for (int c = 0; c < 256; c++) {
            float xc = xn[c];
            ka += xc * Wk[(size_t)c * 256 + tid];
            va += xc * Wv[(size_t)c * 256 + tid];
        }
        vn[i][tid] = va;
        sp[tid] = qrow[tid] * ka;
        __syncthreads();
        if (tid < 8) {
            float s = 0.f;
#pragma unroll
            for (int d = 0; d < 32; d++) s += sp[tid * 32 + d];
            s *= 0.17677669529663687f;
            s = (s > 0.f) ? s : 0.2f * s;
            sc[i][tid] = s;
        }
        __syncthreads();
    }

    {
        const int h = tid & 7, kk = tid >> 3;
        float mx = -1e30f;
#pragma unroll
        for (int i = 0; i < 32; i++) mx = fmaxf(mx, sc[i][h]);
        float ssum = 0.f;
#pragma unroll
        for (int i = 0; i < 32; i++) ssum += __expf(sc[i][h] - mx);
        pwv[kk][h] = __expf(sc[kk][h] - mx) / ssum;
    }
    __syncthreads();

    {
        const int h2 = tid >> 5;
        float acc = 0.f;
#pragma unroll 8
        for (int i = 0; i < 32; i++) acc += pwv[i][h2] * vn[i][tid];
        hd[tid] = acc;
    }
    __syncthreads();

    {
        const int c = tid & 31, ch = tid >> 5;
        float p = 0.f;
#pragma unroll
        for (int i = 0; i < 32; i++) { int r = ch * 32 + i; p += hd[r] * Wp[r * 32 + c]; }
        red[ch][c] = p;
    }
    __syncthreads();

    if (tid < 32) {
        float o = 0.f;
#pragma unroll
        for (int i = 0; i < 8; i++) o += red[i][tid];
        out[(size_t)bj * 32 + tid] = o;
    }
}

extern "C" void kernel_launch(void* const* d_in, const int* in_sizes, int n_in,
                              void* d_out, int out_size, void* d_ws, size_t ws_size,
                              hipStream_t stream) {
    const float* x   = (const float*)d_in[0];
    const int*   nbr = (const int*)d_in[1];
    const float* Wq  = (const float*)d_in[2];
    const float* Wk  = (const float*)d_in[3];
    const float* Wv  = (const float*)d_in[4];
    const float* Wp  = (const float*)d_in[5];
    float*       out = (float*)d_out;

    const size_t ME   = (size_t)16384 * 256;
    const size_t need = (4 * ME + 3 * 65536) * sizeof(unsigned short);  // ~34 MB

    if (ws_size >= need) {
        unsigned short* q  = (unsigned short*)d_ws;
        unsigned short* k  = q + ME;
        unsigned short* vp = k + ME;
        unsigned short* xb = vp + ME;
        unsigned short* Wt = xb + ME;

        prep<<<4096 + 768, 256, 0, stream>>>(x, Wq, Wk, Wv, Wp, xb, Wt);
        qkv_mfma<<<dim3(128, 2, 3), 256, 0, stream>>>(xb, Wt, q, k, vp);
        attn_wave<<<4096, 256, 0, stream>>>(q, k, vp, nbr, out);
    } else {
        fused_all<<<16384, 256, 0, stream>>>(x, nbr, Wq, Wk, Wv, Wp, out);
    }
}

// Round 3
// 118.098 us; speedup vs baseline: 1.0465x; 1.0098x over previous
//
#include <hip/hip_runtime.h>
#include <hip/hip_bf16.h>

// MHGAT: B=8, J=2048, C=256, K=32, H=8, D=32; M = B*J = 16384
// World: all float tensors fp32; nbr int32; out fp32.
// Round 15: r14 base (119.3) + qkv GEMM rebuilt:
//  * 16-way LDS bank conflict fix: both-sides XOR swizzle (linear LDS dest
//    for global_load_lds, pre-swizzled GLOBAL source col, same involution
//    on ds_read addr)  -> 2-way (free).
//  * BK=32 double-buffered (2x16KB), T3-minimum schedule: stage(t+1) ->
//    ds_read(t)+MFMA -> one __syncthreads()/step (its implicit vmcnt(0)
//    is the drain). Load latency hides under compute + TLP.
//  * z-fused 1-D grid (768 blocks) + bijective XCD swizzle; the 6 blocks
//    sharing an A row-panel are consecutive on one XCD's L2.
// attn_wave / prep unchanged from r14 (Q/K f16 + fdot2 kept).

typedef short bf16x8 __attribute__((ext_vector_type(8)));
typedef float f32x4  __attribute__((ext_vector_type(4)));
typedef float f32x2  __attribute__((ext_vector_type(2)));
typedef _Float16 h16x2 __attribute__((ext_vector_type(2)));

__device__ __forceinline__ float bf2f(unsigned short u) {
    union { unsigned int i; float f; } c; c.i = ((unsigned int)u) << 16; return c.f;
}
__device__ __forceinline__ unsigned short f2bf(float f) {
    union { float f; unsigned int i; } c; c.f = f;
    unsigned int r = c.i + 0x7FFFu + ((c.i >> 16) & 1u);  // RNE
    return (unsigned short)(r >> 16);
}
__device__ __forceinline__ unsigned short f2h(float f) {
    union { _Float16 h; unsigned short u; } c; c.h = (_Float16)f;  // v_cvt_f16_f32 RNE
    return c.u;
}
// 2 bf16 packed in a dword -> 2 fp32 with exactly 2 bit-ops.
__device__ __forceinline__ f32x2 upk(unsigned int u) {
    union { unsigned int i; float f; } lo, hi;
    lo.i = u << 16;
    hi.i = u & 0xffff0000u;
    return (f32x2){lo.f, hi.f};
}

// packed-f16 dot2 with f32 accumulate: one v_dot2_f32_f16 when available.
#if defined(__has_builtin)
#if __has_builtin(__builtin_amdgcn_fdot2)
#define HAVE_FDOT2 1
#endif
#endif
__device__ __forceinline__ float dot2acc(unsigned int a, unsigned int b, float acc) {
#ifdef HAVE_FDOT2
    union { unsigned int u; h16x2 v; } ca, cb;
    ca.u = a; cb.u = b;
    return __builtin_amdgcn_fdot2(ca.v, cb.v, acc, false);
#else
    union { unsigned int u; _Float16 h[2]; } ca, cb;
    ca.u = a; cb.u = b;
    return acc + (float)ca.h[0] * (float)cb.h[0] + (float)ca.h[1] * (float)cb.h[1];
#endif
}

__device__ __forceinline__ void gld_lds16(void* lds, const void* g) {
    __builtin_amdgcn_global_load_lds(
        (const __attribute__((address_space(1))) unsigned int*)g,
        (__attribute__((address_space(3))) unsigned int*)lds,
        16, 0, 0);
}

// ---------------------------------------------------------------------------
// Prep (unchanged): x fp32->bf16; Wq/Wk transposed bf16; Weff = Wv@Wp folded.
// ---------------------------------------------------------------------------
__global__ __launch_bounds__(256) void prep(
    const float* __restrict__ x,
    const float* __restrict__ Wq, const float* __restrict__ Wk,
    const float* __restrict__ Wv, const float* __restrict__ Wp,
    unsigned short* __restrict__ xb, unsigned short* __restrict__ Wt)
{
    const int blk = blockIdx.x, tid = threadIdx.x;
    if (blk < 4096) {
        int t = blk * 256 + tid;
        float4 f = ((const float4*)x)[t];
        ushort4 u;
        u.x = f2bf(f.x); u.y = f2bf(f.y); u.z = f2bf(f.z); u.w = f2bf(f.w);
        ((ushort4*)xb)[t] = u;
        return;
    }
    int wi = blk - 4096;
    int w = wi >> 8, n = wi & 255, t = tid;       // t = k index
    if (w == 0) {
        Wt[(size_t)n * 256 + t] = f2bf(Wq[(size_t)t * 256 + n]);
    } else if (w == 1) {
        Wt[(size_t)(256 + n) * 256 + t] = f2bf(Wk[(size_t)t * 256 + n]);
    } else {
        int h = n >> 5, c = n & 31;
        float acc = 0.f;
#pragma unroll
        for (int d = 0; d < 32; d++)
            acc += Wv[(size_t)t * 256 + h * 32 + d] * Wp[(size_t)(h * 32 + d) * 32 + c];
        Wt[(size_t)(512 + n) * 256 + t] = f2bf(acc);
    }
}

// ---------------------------------------------------------------------------
// QKV GEMM v3: xb[16384,256]bf16 @ Wt[768,256]^T -> Y[16384,768].
// 768 blocks (XCD-swizzled), 128x128 tile, BK=32 double-buffered, swizzled
// LDS (conflict-free ds_read_b128). cols 0..255 -> Q (f16), 256..511 -> K
// (f16), 512..767 -> VP (bf16).
// ---------------------------------------------------------------------------
__global__ __launch_bounds__(256) void qkv_mfma(
    const unsigned short* __restrict__ xb,
    const unsigned short* __restrict__ Wt,
    unsigned short* __restrict__ Q, unsigned short* __restrict__ Kp,
    unsigned short* __restrict__ VP)
{
    // [2 bufs][128 rows][64 B]: 16 KB per matrix, 32 KB total.
    __shared__ uint4 AlsV[1024];
    __shared__ uint4 BlsV[1024];

    // bijective XCD swizzle (768 % 8 == 0): consecutive wg share a row-panel.
    const int bid = blockIdx.x;
    const int wg  = (bid & 7) * 96 + (bid >> 3);
    const int rt  = wg / 6;            // row tile 0..127
    const int ct  = wg % 6;            // col tile 0..5 (z = ct>>1)
    const int row0 = rt * 128;

    unsigned short* Y = (ct < 2) ? Q : (ct < 4) ? Kp : VP;
    const bool as_f16 = (ct < 4);
    const int  col0   = (ct & 1) * 128;         // col within the 256-wide output

    const int tid  = threadIdx.x;
    const int w    = tid >> 6, l = tid & 63;
    const int wm   = (w >> 1) * 64, wn = (w & 1) * 64;
    const int lm   = l & 15, quad = l >> 4;
    const int swz  = (lm >> 1) & 3;             // read-side XOR (matches source)

    f32x4 acc[4][4];
#pragma unroll
    for (int i = 0; i < 4; i++)
#pragma unroll
        for (int j = 0; j < 4; j++) acc[i][j] = (f32x4){0.f, 0.f, 0.f, 0.f};

    const char* Ab = (const char*)(xb + (size_t)row0 * 256);
    const char* Bb = (const char*)(Wt + (size_t)(ct * 128) * 256);

    // stage one BK=32 tile (A+B) into buffer `buf`; global source col is
    // pre-swizzled so linear LDS holds the swizzled layout (rule #21).
    auto stage = [&](int t, int buf) {
#pragma unroll
        for (int i = 0; i < 2; i++) {
            int cid = i * 256 + tid;            // 16-B chunk id, 512 per matrix
            int r   = cid >> 2;                 // tile row 0..127
            int cs  = cid & 3;                  // stored col16
            int c   = cs ^ ((r >> 1) & 3);      // fetched col16
            size_t go = (size_t)r * 512 + (size_t)t * 64 + (size_t)c * 16;
            gld_lds16((char*)AlsV + buf * 8192 + cid * 16, Ab + go);
            gld_lds16((char*)BlsV + buf * 8192 + cid * 16, Bb + go);
        }
    };

    stage(0, 0);
    __syncthreads();                            // implicit vmcnt(0) drains tile 0

    int cur = 0;
    for (int t = 0; t < 8; ++t) {
        if (t < 7) stage(t + 1, cur ^ 1);       // issue BEFORE compute (T3)

        const char* Abase = (const char*)AlsV + cur * 8192;
        const char* Bbase = (const char*)BlsV + cur * 8192;
        bf16x8 a[4], b[4];
#pragma unroll
        for (int tm = 0; tm < 4; tm++) {
            int R = wm + tm * 16 + lm;
            a[tm] = *(const bf16x8*)(Abase + R * 64 + ((quad ^ swz) << 4));
        }
#pragma unroll
        for (int tn = 0; tn < 4; tn++) {
            int R = wn + tn * 16 + lm;
            b[tn] = *(const bf16x8*)(Bbase + R * 64 + ((quad ^ swz) << 4));
        }
#pragma unroll
        for (int tm = 0; tm < 4; tm++)
#pragma unroll
            for (int tn = 0; tn < 4; tn++)
                acc[tm][tn] = __builtin_amdgcn_mfma_f32_16x16x32_bf16(
                    a[tm], b[tn], acc[tm][tn], 0, 0, 0);

        __syncthreads();                        // drains stage(t+1) + joins
        cur ^= 1;
    }

#pragma unroll
    for (int tm = 0; tm < 4; tm++) {
        int rbase = row0 + wm + tm * 16 + quad * 4;
#pragma unroll
        for (int tn = 0; tn < 4; tn++) {
            int col = col0 + wn + tn * 16 + lm;
            if (as_f16) {
#pragma unroll
                for (int r = 0; r < 4; r++)
                    Y[(size_t)(rbase + r) * 256 + col] = f2h(acc[tm][tn][r]);
            } else {
#pragma unroll
                for (int r = 0; r < 4; r++)
                    Y[(size_t)(rbase + r) * 256 + col] = f2bf(acc[tm][tn][r]);
            }
        }
    }
}

// ---------------------------------------------------------------------------
// Attention v10 (unchanged from r14): ONE WAVE per (b,j). 4096 blocks x 256.
// Zero barriers, zero LDS. XCD swizzle: b = blk&7.
// ---------------------------------------------------------------------------
__global__ __launch_bounds__(256) void attn_wave(
    const unsigned short* __restrict__ qb,   // [16384,256] f16
    const unsigned short* __restrict__ kb,   // [16384,256] f16
    const unsigned short* __restrict__ vp,   // [16384,256] bf16 (VP = v@Wp)
    const int*            __restrict__ nbr,  // [16384,32]
    float*                __restrict__ out)  // [16384,32] fp32
{
    const int beta = blockIdx.x;
    const int b    = beta & 7;
    const int jt   = beta >> 3;
    const int tid  = threadIdx.x;
    const int w    = tid >> 6;
    const int l    = tid & 63;
    const int lh   = l & 31;
    const int h5   = l >> 5;
    const int bj   = (b << 11) + jt * 4 + w;
    const size_t bbase = (size_t)b << 19;        // b*2048*256 elements
    const int* nrow = nbr + (size_t)bj * 32;

    // all 32 neighbor offsets: lane lh holds nbr[lh]; distribute via shfl.
    int ko = nrow[lh] << 8;                      // element offset of row
    int koff[16];
#pragma unroll
    for (int r = 0; r < 16; r++) koff[r] = __shfl(ko, 2 * r + h5);

    // q fragment (packed f16, 8 elems at lh*8)
    uint4 qu = *(const uint4*)(qb + (size_t)bj * 256 + lh * 8);

    // ---- Phase A: 16 k-row loads (batched, vmcnt-counted) ----
    uint4 kr[16];
#pragma unroll
    for (int r = 0; r < 16; r++)
        kr[r] = *(const uint4*)(kb + bbase + koff[r] + lh * 8);

    float s[16];
#pragma unroll
    for (int r = 0; r < 16; r++) {
        float a = 0.f;
        a = dot2acc(kr[r].x, qu.x, a);
        a = dot2acc(kr[r].y, qu.y, a);
        a = dot2acc(kr[r].z, qu.z, a);
        a = dot2acc(kr[r].w, qu.w, a);
        a += __shfl_xor(a, 1);
        a += __shfl_xor(a, 2);                   // score dup'd across 4 sub-lanes
        a *= 0.17677669529663687f;               // 1/sqrt(32)
        s[r] = (a > 0.f) ? a : 0.2f * a;         // leaky_relu 0.2
    }

    // ---- issue vp loads BEFORE softmax ALU (latency hides under it) ----
    uint4 vr[16];
#pragma unroll
    for (int r = 0; r < 16; r++)
        vr[r] = *(const uint4*)(vp + bbase + koff[r] + lh * 8);

    // ---- softmax per head over 32 rows (16 in-lane + cross-half xor-32) --
    float m = s[0];
#pragma unroll
    for (int r = 1; r < 16; r++) m = fmaxf(m, s[r]);
    m = fmaxf(m, __shfl_xor(m, 32));
    float sum = 0.f;
#pragma unroll
    for (int r = 0; r < 16; r++) { s[r] = __expf(s[r] - m); sum += s[r]; }
    sum += __shfl_xor(sum, 32);
    const float inv = 1.0f / sum;
#pragma unroll
    for (int r = 0; r < 16; r++) s[r] *= inv;    // every lane owns its weights

    // ---- Phase B: weighted accumulate over this lane's 16 rows ----
    f32x2 a0 = (f32x2){0.f, 0.f}, a1 = a0, a2 = a0, a3 = a0;
#pragma unroll
    for (int r = 0; r < 16; r++) {
        const f32x2 w2 = (f32x2){s[r], s[r]};
        a0 += upk(vr[r].x) * w2;
        a1 += upk(vr[r].y) * w2;
        a2 += upk(vr[r].z) * w2;
        a3 += upk(vr[r].w) * w2;
    }

    // ---- merge: halves (xor 32), then heads (xor 4,8,16) ----
    float o[8] = {a0.x, a0.y, a1.x, a1.y, a2.x, a2.y, a3.x, a3.y};
#pragma unroll
    for (int i = 0; i < 8; i++) o[i] += __shfl_xor(o[i], 32);
#pragma unroll
    for (int i = 0; i < 8; i++) o[i] += __shfl_xor(o[i], 4);
#pragma unroll
    for (int i = 0; i < 8; i++) o[i] += __shfl_xor(o[i], 8);
#pragma unroll
    for (int i = 0; i < 8; i++) o[i] += __shfl_xor(o[i], 16);

    if (l < 4) {                                 // sub = l, dims l*8..l*8+7
        float* op = out + (size_t)bj * 32 + l * 8;
        *(float4*)(op)     = make_float4(o[0], o[1], o[2], o[3]);
        *(float4*)(op + 4) = make_float4(o[4], o[5], o[6], o[7]);
    }
}

// ---------------------------------------------------------------------------
// Tier 0 fallback (tiny ws): fully fused fp32, zero workspace. Slow, correct.
// ---------------------------------------------------------------------------
__global__ __launch_bounds__(256) void fused_all(
    const float* __restrict__ X, const int* __restrict__ nbr,
    const float* __restrict__ Wq, const float* __restrict__ Wk,
    const float* __restrict__ Wv, const float* __restrict__ Wp,
    float* __restrict__ out)
{
    __shared__ float xr[256], qrow[256], xn[256];
    __shared__ float vn[32][256];
    __shared__ int   nb[32];
    __shared__ float sc[32][8], pwv[32][8];
    __shared__ float sp[256], hd[256];
    __shared__ float red[8][32];

    const int bj = blockIdx.x, b = bj >> 11, tid = threadIdx.x;

    xr[tid] = X[(size_t)bj * 256 + tid];
    if (tid < 32) nb[tid] = nbr[(size_t)bj * 32 + tid];
    __syncthreads();

    {
        float acc = 0.f;
#pragma unroll 8
        for (int c = 0; c < 256; c++) acc += xr[c] * Wq[(size_t)c * 256 + tid];
        qrow[tid] = acc;
    }
    __syncthreads();

    for (int i = 0; i < 32; i++) {
        size_t r = (size_t)(b * 2048 + nb[i]);
        xn[tid] = X[r * 256 + tid];
        __syncthreads();
        float ka = 0.f, va = 0.f;
#pragma unroll 8
        for (int c = 0; c < 256; c++) {
            float xc = xn[c];
            ka += xc * Wk[(size_t)c * 256 + tid];
            va += xc * Wv[(size_t)c * 256 + tid];
        }
        vn[i][tid] = va;
        sp[tid] = qrow[tid] * ka;
        __syncthreads();
        if (tid < 8) {
            float s = 0.f;
#pragma unroll
            for (int d = 0; d < 32; d++) s += sp[tid * 32 + d];
            s *= 0.17677669529663687f;
            s = (s > 0.f) ? s : 0.2f * s;
            sc[i][tid] = s;
        }
        __syncthreads();
    }

    {
        const int h = tid & 7, kk = tid >> 3;
        float mx = -1e30f;
#pragma unroll
        for (int i = 0; i < 32; i++) mx = fmaxf(mx, sc[i][h]);
        float ssum = 0.f;
#pragma unroll
        for (int i = 0; i < 32; i++) ssum += __expf(sc[i][h] - mx);
        pwv[kk][h] = __expf(sc[kk][h] - mx) / ssum;
    }
    __syncthreads();

    {
        const int h2 = tid >> 5;
        float acc = 0.f;
#pragma unroll 8
        for (int i = 0; i < 32; i++) acc += pwv[i][h2] * vn[i][tid];
        hd[tid] = acc;
    }
    __syncthreads();

    {
        const int c = tid & 31, ch = tid >> 5;
        float p = 0.f;
#pragma unroll
        for (int i = 0; i < 32; i++) { int r = ch * 32 + i; p += hd[r] * Wp[r * 32 + c]; }
        red[ch][c] = p;
    }
    __syncthreads();

    if (tid < 32) {
        float o = 0.f;
#pragma unroll
        for (int i = 0; i < 8; i++) o += red[i][tid];
        out[(size_t)bj * 32 + tid] = o;
    }
}

extern "C" void kernel_launch(void* const* d_in, const int* in_sizes, int n_in,
                              void* d_out, int out_size, void* d_ws, size_t ws_size,
                              hipStream_t stream) {
    const float* x   = (const float*)d_in[0];
    const int*   nbr = (const int*)d_in[1];
    const float* Wq  = (const float*)d_in[2];
    const float* Wk  = (const float*)d_in[3];
    const float* Wv  = (const float*)d_in[4];
    const float* Wp  = (const float*)d_in[5];
    float*       out = (float*)d_out;

    const size_t ME   = (size_t)16384 * 256;
    const size_t need = (4 * ME + 3 * 65536) * sizeof(unsigned short);  // ~34 MB

    if (ws_size >= need) {
        unsigned short* q  = (unsigned short*)d_ws;
        unsigned short* k  = q + ME;
        unsigned short* vp = k + ME;
        unsigned short* xb = vp + ME;
        unsigned short* Wt = xb + ME;

        prep<<<4096 + 768, 256, 0, stream>>>(x, Wq, Wk, Wv, Wp, xb, Wt);
        qkv_mfma<<<768, 256, 0, stream>>>(xb, Wt, q, k, vp);
        attn_wave<<<4096, 256, 0, stream>>>(q, k, vp, nbr, out);
    } else {
        fused_all<<<16384, 256, 0, stream>>>(x, nbr, Wq, Wk, Wv, Wp, out);
    }
}

// Round 4
// 114.591 us; speedup vs baseline: 1.0785x; 1.0306x over previous
//
#include <hip/hip_runtime.h>
#include <hip/hip_bf16.h>

// MHGAT: B=8, J=2048, C=256, K=32, H=8, D=32; M = B*J = 16384
// World: all float tensors fp32; nbr int32; out fp32.
// Round 16: r15 base (118.1). Budget model revised: ~90 us of the measured
// window is harness ws-poison fill; controllable slice ~28 us. This round
// removes pipeline fat:
//  * prep's x->bf16 pass deleted; qkv stages A straight from fp32 x
//    (reg-stage + RNE cvt + swizzled ds_write_b128, T14 issue-early/
//    write-late so the vmcnt wait hides under the MFMAs). -17 MB HBM.
//  * qkv epilogue: LDS-bounce (XOR-swizzled, conflict-free) -> 8 coalesced
//    global_store_dwordx4 per thread instead of 64 scalar 2-B stores.
//  * prep shrinks to the Wt build only (768 blocks).
// attn_wave unchanged from r14 (at its L2-gather floor).

typedef short bf16x8 __attribute__((ext_vector_type(8)));
typedef float f32x4  __attribute__((ext_vector_type(4)));
typedef float f32x2  __attribute__((ext_vector_type(2)));
typedef _Float16 h16x2 __attribute__((ext_vector_type(2)));

__device__ __forceinline__ unsigned short f2bf(float f) {
    union { float f; unsigned int i; } c; c.f = f;
    unsigned int r = c.i + 0x7FFFu + ((c.i >> 16) & 1u);  // RNE
    return (unsigned short)(r >> 16);
}
__device__ __forceinline__ unsigned short f2h(float f) {
    union { _Float16 h; unsigned short u; } c; c.h = (_Float16)f;  // v_cvt_f16_f32 RNE
    return c.u;
}
// 2 bf16 packed in a dword -> 2 fp32 with exactly 2 bit-ops.
__device__ __forceinline__ f32x2 upk(unsigned int u) {
    union { unsigned int i; float f; } lo, hi;
    lo.i = u << 16;
    hi.i = u & 0xffff0000u;
    return (f32x2){lo.f, hi.f};
}

// packed-f16 dot2 with f32 accumulate: one v_dot2_f32_f16 when available.
#if defined(__has_builtin)
#if __has_builtin(__builtin_amdgcn_fdot2)
#define HAVE_FDOT2 1
#endif
#endif
__device__ __forceinline__ float dot2acc(unsigned int a, unsigned int b, float acc) {
#ifdef HAVE_FDOT2
    union { unsigned int u; h16x2 v; } ca, cb;
    ca.u = a; cb.u = b;
    return __builtin_amdgcn_fdot2(ca.v, cb.v, acc, false);
#else
    union { unsigned int u; _Float16 h[2]; } ca, cb;
    ca.u = a; cb.u = b;
    return acc + (float)ca.h[0] * (float)cb.h[0] + (float)ca.h[1] * (float)cb.h[1];
#endif
}

__device__ __forceinline__ void gld_lds16(void* lds, const void* g) {
    __builtin_amdgcn_global_load_lds(
        (const __attribute__((address_space(1))) unsigned int*)g,
        (__attribute__((address_space(3))) unsigned int*)lds,
        16, 0, 0);
}

// ---------------------------------------------------------------------------
// Prep v2 (Wt only, 768 blocks): Wq/Wk transposed bf16; Weff = Wv@Wp folded.
// ---------------------------------------------------------------------------
__global__ __launch_bounds__(256) void prep(
    const float* __restrict__ Wq, const float* __restrict__ Wk,
    const float* __restrict__ Wv, const float* __restrict__ Wp,
    unsigned short* __restrict__ Wt)
{
    const int wi = blockIdx.x, tid = threadIdx.x;
    const int w = wi >> 8, n = wi & 255, t = tid;       // t = k index
    if (w == 0) {
        Wt[(size_t)n * 256 + t] = f2bf(Wq[(size_t)t * 256 + n]);
    } else if (w == 1) {
        Wt[(size_t)(256 + n) * 256 + t] = f2bf(Wk[(size_t)t * 256 + n]);
    } else {
        int h = n >> 5, c = n & 31;
        float acc = 0.f;
#pragma unroll
        for (int d = 0; d < 32; d++)
            acc += Wv[(size_t)t * 256 + h * 32 + d] * Wp[(size_t)(h * 32 + d) * 32 + c];
        Wt[(size_t)(512 + n) * 256 + t] = f2bf(acc);
    }
}

// ---------------------------------------------------------------------------
// QKV GEMM v4: x[16384,256]fp32 @ Wt[768,256]^T -> Y[16384,768].
// 768 blocks (bijective XCD swizzle), 128x128 tile, BK=32 double-buffered.
// A staged from fp32 x: reg-load (issue-early) -> RNE cvt -> swizzled
// ds_write_b128 (write-late, after the MFMAs). B staged via global_load_lds
// with pre-swizzled source col. Epilogue: swizzled LDS bounce -> coalesced
// dwordx4 stores. cols: ct 0,1 -> Q (f16); 2,3 -> K (f16); 4,5 -> VP (bf16).
// ---------------------------------------------------------------------------
__global__ __launch_bounds__(256) void qkv_mfma(
    const float* __restrict__ x,
    const unsigned short* __restrict__ Wt,
    unsigned short* __restrict__ Q, unsigned short* __restrict__ Kp,
    unsigned short* __restrict__ VP)
{
    __shared__ uint4 LDSbuf[2048];   // 32 KB: A dbuf [0,16K) | B dbuf [16K,32K)

    const int bid = blockIdx.x;
    const int wg  = (bid & 7) * 96 + (bid >> 3);   // bijective (768 % 8 == 0)
    const int rt  = wg / 6;                        // row tile 0..127
    const int ct  = wg % 6;                        // col tile 0..5
    const int row0 = rt * 128;

    unsigned short* Y = (ct < 2) ? Q : (ct < 4) ? Kp : VP;
    const bool as_f16 = (ct < 4);
    const int  col0   = (ct & 1) * 128;

    const int tid  = threadIdx.x;
    const int w    = tid >> 6, l = tid & 63;
    const int wm   = (w >> 1) * 64, wn = (w & 1) * 64;
    const int lm   = l & 15, quad = l >> 4;
    const int swz  = (lm >> 1) & 3;                // read-side XOR (matches store)

    f32x4 acc[4][4];
#pragma unroll
    for (int i = 0; i < 4; i++)
#pragma unroll
        for (int j = 0; j < 4; j++) acc[i][j] = (f32x4){0.f, 0.f, 0.f, 0.f};

    const float* xA = x + (size_t)row0 * 256;
    const char*  Bb = (const char*)(Wt + (size_t)(ct * 128) * 256);

    // this thread's two A chunks: cid = (row r)*4 + (stored col16 cs);
    // chunk holds global col16 c = cs ^ ((r>>1)&3)  (both-sides swizzle).
    int ar[2], ac[2];
#pragma unroll
    for (int i = 0; i < 2; i++) {
        int cid = i * 256 + tid;
        ar[i] = cid >> 2;
        ac[i] = (cid & 3) ^ ((ar[i] >> 1) & 3);
    }

    float4 areg[2][2];
    auto a_issue = [&](int t) {
#pragma unroll
        for (int i = 0; i < 2; i++) {
            const float* s = xA + (size_t)ar[i] * 256 + t * 32 + ac[i] * 8;
            areg[i][0] = *(const float4*)(s);
            areg[i][1] = *(const float4*)(s + 4);
        }
    };
    auto a_write = [&](int buf) {
#pragma unroll
        for (int i = 0; i < 2; i++) {
            int cid = i * 256 + tid;
            uint4 v;
            v.x = (unsigned int)f2bf(areg[i][0].x) | ((unsigned int)f2bf(areg[i][0].y) << 16);
            v.y = (unsigned int)f2bf(areg[i][0].z) | ((unsigned int)f2bf(areg[i][0].w) << 16);
            v.z = (unsigned int)f2bf(areg[i][1].x) | ((unsigned int)f2bf(areg[i][1].y) << 16);
            v.w = (unsigned int)f2bf(areg[i][1].z) | ((unsigned int)f2bf(areg[i][1].w) << 16);
            *(uint4*)((char*)LDSbuf + buf * 8192 + cid * 16) = v;
        }
    };
    auto b_stage = [&](int t, int buf) {
#pragma unroll
        for (int i = 0; i < 2; i++) {
            int cid = i * 256 + tid;
            int r = cid >> 2, cs = cid & 3;
            int c = cs ^ ((r >> 1) & 3);
            gld_lds16((char*)LDSbuf + 16384 + buf * 8192 + cid * 16,
                      Bb + (size_t)r * 512 + (size_t)t * 64 + (size_t)c * 16);
        }
    };

    a_issue(0);
    b_stage(0, 0);
    a_write(0);
    __syncthreads();                               // drains vm (B) + lgkm (A)

    int cur = 0;
    for (int t = 0; t < 8; ++t) {
        if (t < 7) { a_issue(t + 1); b_stage(t + 1, cur ^ 1); }

        const char* Abase = (const char*)LDSbuf + cur * 8192;
        const char* Bbase = (const char*)LDSbuf + 16384 + cur * 8192;
        bf16x8 a[4], b[4];
#pragma unroll
        for (int tm = 0; tm < 4; tm++) {
            int R = wm + tm * 16 + lm;
            a[tm] = *(const bf16x8*)(Abase + R * 64 + ((quad ^ swz) << 4));
        }
#pragma unroll
        for (int tn = 0; tn < 4; tn++) {
            int R = wn + tn * 16 + lm;
            b[tn] = *(const bf16x8*)(Bbase + R * 64 + ((quad ^ swz) << 4));
        }
#pragma unroll
        for (int tm = 0; tm < 4; tm++)
#pragma unroll
            for (int tn = 0; tn < 4; tn++)
                acc[tm][tn] = __builtin_amdgcn_mfma_f32_16x16x32_bf16(
                    a[tm], b[tn], acc[tm][tn], 0, 0, 0);

        if (t < 7) a_write(cur ^ 1);               // vmcnt wait lands here (hidden)

        __syncthreads();
        cur ^= 1;
    }

    // ---- epilogue: swizzled LDS bounce -> coalesced 16-B stores ----
    unsigned short* ep = (unsigned short*)LDSbuf;  // 128x128 ushort = 32 KB
#pragma unroll
    for (int tm = 0; tm < 4; tm++)
#pragma unroll
        for (int tn = 0; tn < 4; tn++)
#pragma unroll
            for (int r = 0; r < 4; r++) {
                int rr  = wm + tm * 16 + quad * 4 + r;
                int col = wn + tn * 16 + lm;
                unsigned short u = as_f16 ? f2h(acc[tm][tn][r]) : f2bf(acc[tm][tn][r]);
                int byte = rr * 256 + ((((col >> 3) ^ (rr & 15))) << 4) + (col & 7) * 2;
                *(unsigned short*)((char*)ep + byte) = u;
            }
    __syncthreads();
#pragma unroll
    for (int it = 0; it < 8; it++) {
        int id = it * 256 + tid;
        int r2 = id >> 4, cc = id & 15;
        uint4 v = *(const uint4*)((char*)ep + r2 * 256 + ((cc ^ (r2 & 15)) << 4));
        *(uint4*)(Y + (size_t)(row0 + r2) * 256 + col0 + cc * 8) = v;
    }
}

// ---------------------------------------------------------------------------
// Attention v10 (unchanged from r14): ONE WAVE per (b,j). 4096 blocks x 256.
// Zero barriers, zero LDS. XCD swizzle: b = blk&7.
// ---------------------------------------------------------------------------
__global__ __launch_bounds__(256) void attn_wave(
    const unsigned short* __restrict__ qb,   // [16384,256] f16
    const unsigned short* __restrict__ kb,   // [16384,256] f16
    const unsigned short* __restrict__ vp,   // [16384,256] bf16 (VP = v@Wp)
    const int*            __restrict__ nbr,  // [16384,32]
    float*                __restrict__ out)  // [16384,32] fp32
{
    const int beta = blockIdx.x;
    const int b    = beta & 7;
    const int jt   = beta >> 3;
    const int tid  = threadIdx.x;
    const int w    = tid >> 6;
    const int l    = tid & 63;
    const int lh   = l & 31;
    const int h5   = l >> 5;
    const int bj   = (b << 11) + jt * 4 + w;
    const size_t bbase = (size_t)b << 19;        // b*2048*256 elements
    const int* nrow = nbr + (size_t)bj * 32;

    // all 32 neighbor offsets: lane lh holds nbr[lh]; distribute via shfl.
    int ko = nrow[lh] << 8;                      // element offset of row
    int koff[16];
#pragma unroll
    for (int r = 0; r < 16; r++) koff[r] = __shfl(ko, 2 * r + h5);

    // q fragment (packed f16, 8 elems at lh*8)
    uint4 qu = *(const uint4*)(qb + (size_t)bj * 256 + lh * 8);

    // ---- Phase A: 16 k-row loads (batched, vmcnt-counted) ----
    uint4 kr[16];
#pragma unroll
    for (int r = 0; r < 16; r++)
        kr[r] = *(const uint4*)(kb + bbase + koff[r] + lh * 8);

    float s[16];
#pragma unroll
    for (int r = 0; r < 16; r++) {
        float a = 0.f;
        a = dot2acc(kr[r].x, qu.x, a);
        a = dot2acc(kr[r].y, qu.y, a);
        a = dot2acc(kr[r].z, qu.z, a);
        a = dot2acc(kr[r].w, qu.w, a);
        a += __shfl_xor(a, 1);
        a += __shfl_xor(a, 2);                   // score dup'd across 4 sub-lanes
        a *= 0.17677669529663687f;               // 1/sqrt(32)
        s[r] = (a > 0.f) ? a : 0.2f * a;         // leaky_relu 0.2
    }

    // ---- issue vp loads BEFORE softmax ALU (latency hides under it) ----
    uint4 vr[16];
#pragma unroll
    for (int r = 0; r < 16; r++)
        vr[r] = *(const uint4*)(vp + bbase + koff[r] + lh * 8);

    // ---- softmax per head over 32 rows (16 in-lane + cross-half xor-32) --
    float m = s[0];
#pragma unroll
    for (int r = 1; r < 16; r++) m = fmaxf(m, s[r]);
    m = fmaxf(m, __shfl_xor(m, 32));
    float sum = 0.f;
#pragma unroll
    for (int r = 0; r < 16; r++) { s[r] = __expf(s[r] - m); sum += s[r]; }
    sum += __shfl_xor(sum, 32);
    const float inv = 1.0f / sum;
#pragma unroll
    for (int r = 0; r < 16; r++) s[r] *= inv;    // every lane owns its weights

    // ---- Phase B: weighted accumulate over this lane's 16 rows ----
    f32x2 a0 = (f32x2){0.f, 0.f}, a1 = a0, a2 = a0, a3 = a0;
#pragma unroll
    for (int r = 0; r < 16; r++) {
        const f32x2 w2 = (f32x2){s[r], s[r]};
        a0 += upk(vr[r].x) * w2;
        a1 += upk(vr[r].y) * w2;
        a2 += upk(vr[r].z) * w2;
        a3 += upk(vr[r].w) * w2;
    }

    // ---- merge: halves (xor 32), then heads (xor 4,8,16) ----
    float o[8] = {a0.x, a0.y, a1.x, a1.y, a2.x, a2.y, a3.x, a3.y};
#pragma unroll
    for (int i = 0; i < 8; i++) o[i] += __shfl_xor(o[i], 32);
#pragma unroll
    for (int i = 0; i < 8; i++) o[i] += __shfl_xor(o[i], 4);
#pragma unroll
    for (int i = 0; i < 8; i++) o[i] += __shfl_xor(o[i], 8);
#pragma unroll
    for (int i = 0; i < 8; i++) o[i] += __shfl_xor(o[i], 16);

    if (l < 4) {                                 // sub = l, dims l*8..l*8+7
        float* op = out + (size_t)bj * 32 + l * 8;
        *(float4*)(op)     = make_float4(o[0], o[1], o[2], o[3]);
        *(float4*)(op + 4) = make_float4(o[4], o[5], o[6], o[7]);
    }
}

// ---------------------------------------------------------------------------
// Tier 0 fallback (tiny ws): fully fused fp32, zero workspace. Slow, correct.
// ---------------------------------------------------------------------------
__global__ __launch_bounds__(256) void fused_all(
    const float* __restrict__ X, const int* __restrict__ nbr,
    const float* __restrict__ Wq, const float* __restrict__ Wk,
    const float* __restrict__ Wv, const float* __restrict__ Wp,
    float* __restrict__ out)
{
    __shared__ float xr[256], qrow[256], xn[256];
    __shared__ float vn[32][256];
    __shared__ int   nb[32];
    __shared__ float sc[32][8], pwv[32][8];
    __shared__ float sp[256], hd[256];
    __shared__ float red[8][32];

    const int bj = blockIdx.x, b = bj >> 11, tid = threadIdx.x;

    xr[tid] = X[(size_t)bj * 256 + tid];
    if (tid < 32) nb[tid] = nbr[(size_t)bj * 32 + tid];
    __syncthreads();

    {
        float acc = 0.f;
#pragma unroll 8
        for (int c = 0; c < 256; c++) acc += xr[c] * Wq[(size_t)c * 256 + tid];
        qrow[tid] = acc;
    }
    __syncthreads();

    for (int i = 0; i < 32; i++) {
        size_t r = (size_t)(b * 2048 + nb[i]);
        xn[tid] = X[r * 256 + tid];
        __syncthreads();
        float ka = 0.f, va = 0.f;
#pragma unroll 8
        for (int c = 0; c < 256; c++) {
            float xc = xn[c];
            ka += xc * Wk[(size_t)c * 256 + tid];
            va += xc * Wv[(size_t)c * 256 + tid];
        }
        vn[i][tid] = va;
        sp[tid] = qrow[tid] * ka;
        __syncthreads();
        if (tid < 8) {
            float s = 0.f;
#pragma unroll
            for (int d = 0; d < 32; d++) s += sp[tid * 32 + d];
            s *= 0.17677669529663687f;
            s = (s > 0.f) ? s : 0.2f * s;
            sc[i][tid] = s;
        }
        __syncthreads();
    }

    {
        const int h = tid & 7, kk = tid >> 3;
        float mx = -1e30f;
#pragma unroll
        for (int i = 0; i < 32; i++) mx = fmaxf(mx, sc[i][h]);
        float ssum = 0.f;
#pragma unroll
        for (int i = 0; i < 32; i++) ssum += __expf(sc[i][h] - mx);
        pwv[kk][h] = __expf(sc[kk][h] - mx) / ssum;
    }
    __syncthreads();

    {
        const int h2 = tid >> 5;
        float acc = 0.f;
#pragma unroll 8
        for (int i = 0; i < 32; i++) acc += pwv[i][h2] * vn[i][tid];
        hd[tid] = acc;
    }
    __syncthreads();

    {
        const int c = tid & 31, ch = tid >> 5;
        float p = 0.f;
#pragma unroll
        for (int i = 0; i < 32; i++) { int r = ch * 32 + i; p += hd[r] * Wp[r * 32 + c]; }
        red[ch][c] = p;
    }
    __syncthreads();

    if (tid < 32) {
        float o = 0.f;
#pragma unroll
        for (int i = 0; i < 8; i++) o += red[i][tid];
        out[(size_t)bj * 32 + tid] = o;
    }
}

extern "C" void kernel_launch(void* const* d_in, const int* in_sizes, int n_in,
                              void* d_out, int out_size, void* d_ws, size_t ws_size,
                              hipStream_t stream) {
    const float* x   = (const float*)d_in[0];
    const int*   nbr = (const int*)d_in[1];
    const float* Wq  = (const float*)d_in[2];
    const float* Wk  = (const float*)d_in[3];
    const float* Wv  = (const float*)d_in[4];
    const float* Wp  = (const float*)d_in[5];
    float*       out = (float*)d_out;

    const size_t ME   = (size_t)16384 * 256;
    const size_t WTE  = (size_t)768 * 256;
    const size_t need = (3 * ME + WTE) * sizeof(unsigned short);  // ~26 MB

    if (ws_size >= need) {
        unsigned short* q  = (unsigned short*)d_ws;
        unsigned short* k  = q + ME;
        unsigned short* vp = k + ME;
        unsigned short* Wt = vp + ME;

        prep<<<768, 256, 0, stream>>>(Wq, Wk, Wv, Wp, Wt);
        qkv_mfma<<<768, 256, 0, stream>>>(x, Wt, q, k, vp);
        attn_wave<<<4096, 256, 0, stream>>>(q, k, vp, nbr, out);
    } else {
        fused_all<<<16384, 256, 0, stream>>>(x, nbr, Wq, Wk, Wv, Wp, out);
    }
}